// Round 3
// baseline (413.278 us; speedup 1.0000x reference)
//
#include <hip/hip_runtime.h>
#include <stdint.h>

typedef _Float16 f16;
typedef _Float16 f16x4 __attribute__((ext_vector_type(4)));
typedef _Float16 f16x8 __attribute__((ext_vector_type(8)));
typedef float f32x4 __attribute__((ext_vector_type(4)));

#define NB 8
#define NN 4096
#define CC 768
#define SCALE_F 0.10206207261596577f  // 96^-0.5

// async global->LDS, 16B per lane; LDS dest = wave-uniform base + lane*16
#define GLDS16(gp, lp)                                                       \
  __builtin_amdgcn_global_load_lds(                                          \
      (__attribute__((address_space(1))) void*)(gp),                         \
      (__attribute__((address_space(3))) void*)(lp), 16, 0, 0)

// ---------------------------------------------------------------------------
// Kernel A: fp32 -> fp16 convert + transpose.
//   x1t[b][c][n] = x1[b][n][c]; x2t[b][d][n] = x2[b][n][d]; x2b = f16(x2)
//
// Rewritten: the old [64][65] f32 pad broke 16B alignment -> 16 scalar
// ds_write_b32 + 16 scalar ds_read_b32 per thread (latency/issue-bound at
// 31% HBM). New: unpadded [64][64] f32 tile with 16B-chunk XOR swizzle
// (chunk ^= row&15, involution applied on write AND read — rule #21):
//   write: one ds_write_b128 per row-chunk; per 16-lane phase the 16
//     swizzled chunks are distinct -> 2-way (free).
//   read:  lane = output column c, row n = w*16+j; swizzle spreads the 64
//     lanes over all 64 dword slots of the row-pair window -> 2-way (free).
// 4+16 conflict-free LDS ops/thread instead of 32 conflicted scalar ones;
// output stores are 32 B contiguous per lane.
// ---------------------------------------------------------------------------
__global__ __launch_bounds__(256) void k_convert(
    const float* __restrict__ x1, const float* __restrict__ x2,
    f16* __restrict__ x1t, f16* __restrict__ x2t, f16* __restrict__ x2b) {
  __shared__ __align__(16) float tile[64 * 64];
  const int which = blockIdx.z >> 3;  // 0: x1, 1: x2
  const int b = blockIdx.z & 7;
  const int n0 = blockIdx.x << 6;
  const int c0 = blockIdx.y << 6;
  const float* src = (which ? x2 : x1) + (size_t)b * NN * CC;
  f16* dt = (which ? x2t : x1t) + (size_t)b * CC * NN;
  const int t = threadIdx.x;
  const int rowi = t >> 4;          // 0..15
  const int chnk = t & 15;          // 16B chunk within row
  const int col4 = chnk << 2;       // 0,4,..,60
  const int swc4 = (chnk ^ rowi) << 2;  // swizzled chunk (r&15 == rowi)
#pragma unroll
  for (int it = 0; it < 4; ++it) {
    const int r = it * 16 + rowi;
    const float4 v =
        *reinterpret_cast<const float4*>(&src[(size_t)(n0 + r) * CC + c0 + col4]);
    *reinterpret_cast<float4*>(&tile[r * 64 + swc4]) =
        v;  // swizzled, 16B-aligned
    if (which) {
      f16x4 o = {(f16)v.x, (f16)v.y, (f16)v.z, (f16)v.w};
      *reinterpret_cast<f16x4*>(
          &x2b[(size_t)b * NN * CC + (size_t)(n0 + r) * CC + c0 + col4]) = o;
    }
  }
  __syncthreads();
  const int c = t & 63;             // output row (channel) this lane owns
  const int w = t >> 6;             // n-chunk of 16
  f16 ob[16];
#pragma unroll
  for (int j = 0; j < 16; ++j) {
    const int n = w * 16 + j;       // n&15 == j
    ob[j] = (f16)tile[n * 64 + (((c >> 2) ^ j) << 2) + (c & 3)];
  }
  f16* o = &dt[(size_t)(c0 + c) * NN + n0 + w * 16];
  *reinterpret_cast<f16x8*>(o) = *reinterpret_cast<f16x8*>(&ob[0]);
  *reinterpret_cast<f16x8*>(o + 8) = *reinterpret_cast<f16x8*>(&ob[8]);
}

// ---------------------------------------------------------------------------
// Kernel B/D: bt-GEMM: C[m][n] (+)= sum_k A[m][k]*B[n][k]
//
// 256x256 block tile, BK=64, 8 waves (2M x 4N), per-wave tile 128x64
// (FLOP per LDS-read byte = 42.7; the 64x64-wave structure was LDS-BW bound).
//
// 2-buffer LDS (128 KiB, 1 block/CU, 2 waves/SIMD), 2 tiles in flight,
// counted vmcnt (never 0 in steady state). See round-2 notes.
//
// LDS swizzle (both-sides involution): k-chunk (16B) XORed with (row&7) on
// BOTH the pre-swizzled global source of global_load_lds and the ds_read
// offset. Conflict-free (verified round 2: SQ_LDS_BANK_CONFLICT = 0).
//
// 1-D grid, batch = xcd (assumes hw xcd = blockIdx.x % 8):
//  SWZ=1 (GEMM1): 3x3 tiles, 8 batches, ksplit=3 UNEVEN (1344/1344/1408,
//                 atomic). grid 216 -> single-round makespan on 256 CUs
//                 (ksplit=2's 144 blocks left 44% of CUs idle).
//  SWZ=2 (GEMM2): 16x3 tiles, 8 batches, no split. grid 384.
// ---------------------------------------------------------------------------
template <bool ATOMIC, int SWZ>
__global__ __launch_bounds__(512, 2) void k_gemm_bt(
    const f16* __restrict__ A, const f16* __restrict__ B,
    float* __restrict__ C, int klen, int lda, int ldb, int ldc,
    size_t sA, size_t sB, size_t sC) {
  __shared__ __align__(16) f16 As[2][256 * 64];
  __shared__ __align__(16) f16 Bs[2][256 * 64];

  const int lin = blockIdx.x;
  const int xcd = lin & 7;
  const int slot = lin >> 3;
  int bx, by, ks;
  const int b = xcd;               // one batch per XCD
  if (SWZ == 1) {
    ks = slot / 9;                 // 3 K-split phases
    const int item = slot % 9;
    bx = item % 3;
    by = item / 3;
  } else {
    ks = 0;
    by = slot % 3;                 // 3 consecutive tiles share the B chunk
    bx = slot / 3;
  }

  const size_t kofs = (size_t)ks * klen;
  int kl = klen;
  if (SWZ == 1 && ks == 2) kl += 64;  // uneven tail: 1344+1344+1408 = 4096

  const f16* Ap = A + (size_t)b * sA + (size_t)by * 256 * lda + kofs;
  const f16* Bp = B + (size_t)b * sB + (size_t)bx * 256 * ldb + kofs;
  float* Cp = C + (size_t)b * sC + (size_t)by * 256 * ldc + bx * 256;

  const int tid = threadIdx.x;
  const int wave = tid >> 6;
  const int lane = tid & 63;
  const int wr = wave >> 2;   // 0/1  -> M half (128 rows)
  const int wn = wave & 3;    // 0..3 -> N quarter (64 cols)

  // --- staging geometry: wave w stages A rows [32w,32w+32) and B rows ditto,
  // as 4 chunks of (8 rows x 64k) = 1KB each. LDS dest is linear
  // (global_load_lds), global source k-chunk is pre-swizzled by row&7.
  const int srow = lane >> 3;                    // 0..7 (row within chunk)
  const int ssw = ((lane & 7) ^ srow) * 8;       // swizzled source k-offset (f16)
  const f16* gA = Ap + (size_t)(wave * 32 + srow) * lda + ssw;
  const f16* gB = Bp + (size_t)(wave * 32 + srow) * ldb + ssw;
  const int cb = wave * 4 * 512;                 // wave's chunk-0 LDS offset (f16)

  // --- fragment read offsets: lane holds row (lane&15), k-chunk (lane>>4),
  // with the same XOR; row&7 == (lane&15)&7 is invariant under +16-row steps.
  const int mrow = lane & 15;
  const int kk = lane >> 4;                      // 0..3
  const int asw = ((kk ^ (mrow & 7)) * 8);
  const int raofs = (wr * 128 + mrow) * 64 + asw;
  const int rbofs = (wn * 64 + mrow) * 64 + asw;

  f32x4 acc[8][4] = {};

  const int nit = kl >> 6;

#define STAGE(bufi)                                                          \
  do {                                                                       \
    _Pragma("unroll") for (int q = 0; q < 4; ++q) {                          \
      GLDS16(gA + (size_t)q * 8 * lda, &As[bufi][cb + q * 512]);             \
      GLDS16(gB + (size_t)q * 8 * ldb, &Bs[bufi][cb + q * 512]);             \
    }                                                                        \
  } while (0)

  // prologue: tiles 0 and 1
  STAGE(0);
  gA += 64; gB += 64;
  STAGE(1);

  for (int it = 0; it < nit; ++it) {
    const int buf = it & 1;
    if (it + 1 < nit)
      asm volatile("s_waitcnt vmcnt(8)" ::: "memory");
    else
      asm volatile("s_waitcnt vmcnt(0)" ::: "memory");
    __builtin_amdgcn_s_barrier();
    __builtin_amdgcn_sched_barrier(0);

    const f16* la = &As[buf][0];
    const f16* lb = &Bs[buf][0];
    f16x8 af[8], bf[4];
    // ---- k-sub 0: reads + MFMA
#pragma unroll
    for (int i = 0; i < 8; ++i)
      af[i] = *reinterpret_cast<const f16x8*>(la + raofs + i * 1024);
#pragma unroll
    for (int j = 0; j < 4; ++j)
      bf[j] = *reinterpret_cast<const f16x8*>(lb + rbofs + j * 1024);
#pragma unroll
    for (int i = 0; i < 8; ++i)
#pragma unroll
      for (int j = 0; j < 4; ++j)
        acc[i][j] = __builtin_amdgcn_mfma_f32_16x16x32_f16(af[i], bf[j],
                                                           acc[i][j], 0, 0, 0);
    // ---- k-sub 1: reads (k-chunk ^4 under the swizzle == offset ^32)
#pragma unroll
    for (int i = 0; i < 8; ++i)
      af[i] = *reinterpret_cast<const f16x8*>(la + ((raofs + i * 1024) ^ 32));
#pragma unroll
    for (int j = 0; j < 4; ++j)
      bf[j] = *reinterpret_cast<const f16x8*>(lb + ((rbofs + j * 1024) ^ 32));
    asm volatile("s_waitcnt lgkmcnt(0)" ::: "memory");
    __builtin_amdgcn_sched_barrier(0);
    __builtin_amdgcn_s_barrier();   // all waves finished reading buf
    __builtin_amdgcn_sched_barrier(0);
    if (it + 2 < nit) {
      gA += 64; gB += 64;
      STAGE(buf);                   // refill just-read buffer with tile t+2
    }
#pragma unroll
    for (int i = 0; i < 8; ++i)
#pragma unroll
      for (int j = 0; j < 4; ++j)
        acc[i][j] = __builtin_amdgcn_mfma_f32_16x16x32_f16(af[i], bf[j],
                                                           acc[i][j], 0, 0, 0);
  }
#undef STAGE

  // C/D layout (verified m89/m91, dtype-independent): col=lane&15, row=(lane>>4)*4+reg
  const int col = lane & 15;
  const int rq = kk * 4;
#pragma unroll
  for (int i = 0; i < 8; ++i) {
    const int r0 = wr * 128 + i * 16 + rq;
#pragma unroll
    for (int j = 0; j < 4; ++j) {
      const int cidx = wn * 64 + j * 16 + col;
#pragma unroll
      for (int r = 0; r < 4; ++r) {
        const float v = acc[i][j][r];
        if (ATOMIC)
          atomicAdd(&Cp[(size_t)(r0 + r) * ldc + cidx], v);
        else
          Cp[(size_t)(r0 + r) * ldc + cidx] = v;
      }
    }
  }
}

// ---------------------------------------------------------------------------
// Kernel C: row softmax over 768 logits (SCALE applied here), fp32 -> fp16.
// ---------------------------------------------------------------------------
__global__ __launch_bounds__(256) void k_softmax(const float* __restrict__ S,
                                                 f16* __restrict__ P) {
  const int row = blockIdx.x * 4 + (threadIdx.x >> 6);
  const int lane = threadIdx.x & 63;
  const float* s = S + (size_t)row * CC;
  float v[12];
#pragma unroll
  for (int j = 0; j < 3; ++j) {
    const float4 t = *reinterpret_cast<const float4*>(&s[j * 256 + lane * 4]);
    v[j * 4 + 0] = t.x * SCALE_F;
    v[j * 4 + 1] = t.y * SCALE_F;
    v[j * 4 + 2] = t.z * SCALE_F;
    v[j * 4 + 3] = t.w * SCALE_F;
  }
  float m = v[0];
#pragma unroll
  for (int j = 1; j < 12; ++j) m = fmaxf(m, v[j]);
#pragma unroll
  for (int off = 32; off >= 1; off >>= 1) m = fmaxf(m, __shfl_xor(m, off, 64));
  float sum = 0.f;
#pragma unroll
  for (int j = 0; j < 12; ++j) {
    v[j] = __expf(v[j] - m);
    sum += v[j];
  }
#pragma unroll
  for (int off = 32; off >= 1; off >>= 1) sum += __shfl_xor(sum, off, 64);
  const float inv = 1.0f / sum;
  f16* p = P + (size_t)row * CC;
#pragma unroll
  for (int j = 0; j < 3; ++j) {
    f16x4 o = {(f16)(v[j * 4 + 0] * inv), (f16)(v[j * 4 + 1] * inv),
               (f16)(v[j * 4 + 2] * inv), (f16)(v[j * 4 + 3] * inv)};
    *reinterpret_cast<f16x4*>(&p[j * 256 + lane * 4]) = o;
  }
}

// ---------------------------------------------------------------------------
extern "C" void kernel_launch(void* const* d_in, const int* in_sizes, int n_in,
                              void* d_out, int out_size, void* d_ws,
                              size_t ws_size, hipStream_t stream) {
  const float* x1 = (const float*)d_in[0];
  const float* x2 = (const float*)d_in[1];
  float* out = (float*)d_out;

  const size_t elems = (size_t)NB * NN * CC;  // 25165824
  // x1t/x2t live in d_out (2 * f16 arrays == out fp32 bytes exactly);
  // GEMM2 overwrites out only after GEMM1 consumed them.
  f16* x1t = (f16*)d_out;
  f16* x2t = x1t + elems;
  char* ws = (char*)d_ws;
  f16* x2b = (f16*)ws;                                     // 50.3 MB
  float* S = (float*)(ws + elems * 2);                     // 18.9 MB
  f16* P = (f16*)(ws + elems * 2 + (size_t)NB * CC * CC * 4);  // 9.4 MB
  const size_t need =
      elems * 2 + (size_t)NB * CC * CC * 4 + (size_t)NB * CC * CC * 2;
  if (ws_size < need) return;  // cannot run without scratch

  // A) convert + transpose
  k_convert<<<dim3(NN / 64, CC / 64, 2 * NB), 256, 0, stream>>>(x1, x2, x1t,
                                                                x2t, x2b);
  // B) S = x1t . x2t^T  (split-K x3 uneven, atomic accumulate; S pre-zeroed)
  hipMemsetAsync(S, 0, (size_t)NB * CC * CC * 4, stream);
  k_gemm_bt<true, 1><<<dim3(9 * NB * 3), 512, 0, stream>>>(
      x1t, x2t, S, 1344, NN, NN, CC, (size_t)CC * NN, (size_t)CC * NN,
      (size_t)CC * CC);
  // C) P = softmax(SCALE * S) as fp16
  k_softmax<<<dim3(NB * CC / 4), 256, 0, stream>>>(S, P);
  // D) out = P . x2b^T
  k_gemm_bt<false, 2><<<dim3(16 * 3 * NB), 512, 0, stream>>>(
      P, x2b, out, CC, CC, CC, NN, (size_t)CC * CC, (size_t)NN * CC,
      (size_t)CC * NN);
}

// Round 4
// 399.292 us; speedup vs baseline: 1.0350x; 1.0350x over previous
//
#include <hip/hip_runtime.h>
#include <stdint.h>

typedef _Float16 f16;
typedef _Float16 f16x4 __attribute__((ext_vector_type(4)));
typedef _Float16 f16x8 __attribute__((ext_vector_type(8)));
typedef float f32x4 __attribute__((ext_vector_type(4)));

#define NB 8
#define NN 4096
#define CC 768
#define SCALE_F 0.10206207261596577f  // 96^-0.5

// async global->LDS, 16B per lane; LDS dest = wave-uniform base + lane*16
#define GLDS16(gp, lp)                                                       \
  __builtin_amdgcn_global_load_lds(                                          \
      (__attribute__((address_space(1))) void*)(gp),                         \
      (__attribute__((address_space(3))) void*)(lp), 16, 0, 0)

// ---------------------------------------------------------------------------
// Kernel A: fp32 -> fp16 convert + transpose.
//   x1t[b][c][n] = x1[b][n][c]; x2t[b][d][n] = x2[b][n][d]; x2b = f16(x2)
//
// v3: round-3 data showed convert is NOT LDS-bound (conflicts 0, VALU 7%)
// but transaction-rate bound on the transposed stores (64 lanes x 16B at
// 8KB stride per instruction -> 64 scattered line-touches/instr, 2.25 TB/s).
// Fix: 128n x 64c tile; read/store assignment gives each output row 16
// consecutive lanes (16B f16x8 each) -> every store instr = 4 rows x 256 B
// CONTIGUOUS. Swizzle re-derived for this read shape: chunk ^= (n>>3)&15
// (puts per-lane u-bits into the bank index; old n&15 got masked out).
//   write: b128, 8 accesses/bank (minimal). read: b32, 2-way (free).
//   global: loads 256B/row, transposed stores 256B/row, x2b 128B/row.
// ---------------------------------------------------------------------------
__global__ __launch_bounds__(256) void k_convert(
    const float* __restrict__ x1, const float* __restrict__ x2,
    f16* __restrict__ x1t, f16* __restrict__ x2t, f16* __restrict__ x2b) {
  __shared__ __align__(16) float tile[128 * 64];  // [n][c-chunk swizzled] 32 KB
  const int which = blockIdx.z >> 3;  // 0: x1, 1: x2
  const int b = blockIdx.z & 7;
  const int n0 = blockIdx.x << 7;     // 128-n tile
  const int c0 = blockIdx.y << 6;     // 64-c tile
  const float* src = (which ? x2 : x1) + (size_t)b * NN * CC;
  f16* dt = (which ? x2t : x1t) + (size_t)b * CC * NN;
  const int t = threadIdx.x;
  const int rowi = t >> 4;          // 0..15 (n within 16-row group)
  const int chnk = t & 15;          // c-chunk (4 f32 = 16B)
  const int col4 = chnk << 2;
#pragma unroll
  for (int it = 0; it < 8; ++it) {
    const int n = it * 16 + rowi;
    const float4 v =
        *reinterpret_cast<const float4*>(&src[(size_t)(n0 + n) * CC + c0 + col4]);
    const int sw = chnk ^ ((n >> 3) & 15);  // swizzled chunk
    *reinterpret_cast<float4*>(&tile[n * 64 + sw * 4]) = v;
    if (which) {
      f16x4 o = {(f16)v.x, (f16)v.y, (f16)v.z, (f16)v.w};
      *reinterpret_cast<f16x4*>(
          &x2b[(size_t)b * NN * CC + (size_t)(n0 + n) * CC + c0 + col4]) = o;
    }
  }
  __syncthreads();
  // transposed read: thread (c, u) packs n = 8u..8u+7 of row c; 4 passes.
  const int u = t & 15;             // n-chunk of 8 (16B f16 out)
  const int crow = t >> 4;          // 0..15
#pragma unroll
  for (int p = 0; p < 4; ++p) {
    const int c = p * 16 + crow;
    f16 ob[8];
#pragma unroll
    for (int j = 0; j < 8; ++j) {
      const int n = u * 8 + j;                 // (n>>3)&15 == u
      const int sw = (c >> 2) ^ u;             // swizzled chunk
      ob[j] = (f16)tile[n * 64 + sw * 4 + (c & 3)];
    }
    *reinterpret_cast<f16x8*>(&dt[(size_t)(c0 + c) * NN + n0 + u * 8]) =
        *reinterpret_cast<f16x8*>(ob);
  }
}

// ---------------------------------------------------------------------------
// Kernel B/D: bt-GEMM: C[m][n] (+)= sum_k A[m][k]*B[n][k]
//
// 256x256 block tile, BK=64, 8 waves (2M x 4N), per-wave tile 128x64
// (FLOP per LDS-read byte = 42.7; the 64x64-wave structure was LDS-BW bound).
//
// 2-buffer LDS (128 KiB, 1 block/CU, 2 waves/SIMD), 2 tiles in flight,
// counted vmcnt (never 0 in steady state). See round-2 notes.
//
// LDS swizzle (both-sides involution): k-chunk (16B) XORed with (row&7) on
// BOTH the pre-swizzled global source of global_load_lds and the ds_read
// offset. Conflict-free (verified round 2: SQ_LDS_BANK_CONFLICT = 0).
//
// 1-D grid, batch = xcd (assumes hw xcd = blockIdx.x % 8):
//  SWZ=1 (GEMM1): 3x3 tiles, 8 batches, ksplit=3 UNEVEN (1344/1344/1408,
//                 atomic). grid 216 -> single-round makespan on 256 CUs.
//  SWZ=2 (GEMM2): 16x3 tiles, 8 batches, no split. grid 384.
// ---------------------------------------------------------------------------
template <bool ATOMIC, int SWZ>
__global__ __launch_bounds__(512, 2) void k_gemm_bt(
    const f16* __restrict__ A, const f16* __restrict__ B,
    float* __restrict__ C, int klen, int lda, int ldb, int ldc,
    size_t sA, size_t sB, size_t sC) {
  __shared__ __align__(16) f16 As[2][256 * 64];
  __shared__ __align__(16) f16 Bs[2][256 * 64];

  const int lin = blockIdx.x;
  const int xcd = lin & 7;
  const int slot = lin >> 3;
  int bx, by, ks;
  const int b = xcd;               // one batch per XCD
  if (SWZ == 1) {
    ks = slot / 9;                 // 3 K-split phases
    const int item = slot % 9;
    bx = item % 3;
    by = item / 3;
  } else {
    ks = 0;
    by = slot % 3;                 // 3 consecutive tiles share the B chunk
    bx = slot / 3;
  }

  const size_t kofs = (size_t)ks * klen;
  int kl = klen;
  if (SWZ == 1 && ks == 2) kl += 64;  // uneven tail: 1344+1344+1408 = 4096

  const f16* Ap = A + (size_t)b * sA + (size_t)by * 256 * lda + kofs;
  const f16* Bp = B + (size_t)b * sB + (size_t)bx * 256 * ldb + kofs;
  float* Cp = C + (size_t)b * sC + (size_t)by * 256 * ldc + bx * 256;

  const int tid = threadIdx.x;
  const int wave = tid >> 6;
  const int lane = tid & 63;
  const int wr = wave >> 2;   // 0/1  -> M half (128 rows)
  const int wn = wave & 3;    // 0..3 -> N quarter (64 cols)

  // --- staging geometry: wave w stages A rows [32w,32w+32) and B rows ditto,
  // as 4 chunks of (8 rows x 64k) = 1KB each. LDS dest is linear
  // (global_load_lds), global source k-chunk is pre-swizzled by row&7.
  const int srow = lane >> 3;                    // 0..7 (row within chunk)
  const int ssw = ((lane & 7) ^ srow) * 8;       // swizzled source k-offset (f16)
  const f16* gA = Ap + (size_t)(wave * 32 + srow) * lda + ssw;
  const f16* gB = Bp + (size_t)(wave * 32 + srow) * ldb + ssw;
  const int cb = wave * 4 * 512;                 // wave's chunk-0 LDS offset (f16)

  // --- fragment read offsets: lane holds row (lane&15), k-chunk (lane>>4),
  // with the same XOR; row&7 == (lane&15)&7 is invariant under +16-row steps.
  const int mrow = lane & 15;
  const int kk = lane >> 4;                      // 0..3
  const int asw = ((kk ^ (mrow & 7)) * 8);
  const int raofs = (wr * 128 + mrow) * 64 + asw;
  const int rbofs = (wn * 64 + mrow) * 64 + asw;

  f32x4 acc[8][4] = {};

  const int nit = kl >> 6;

#define STAGE(bufi)                                                          \
  do {                                                                       \
    _Pragma("unroll") for (int q = 0; q < 4; ++q) {                          \
      GLDS16(gA + (size_t)q * 8 * lda, &As[bufi][cb + q * 512]);             \
      GLDS16(gB + (size_t)q * 8 * ldb, &Bs[bufi][cb + q * 512]);             \
    }                                                                        \
  } while (0)

  // prologue: tiles 0 and 1
  STAGE(0);
  gA += 64; gB += 64;
  STAGE(1);

  for (int it = 0; it < nit; ++it) {
    const int buf = it & 1;
    if (it + 1 < nit)
      asm volatile("s_waitcnt vmcnt(8)" ::: "memory");
    else
      asm volatile("s_waitcnt vmcnt(0)" ::: "memory");
    __builtin_amdgcn_s_barrier();
    __builtin_amdgcn_sched_barrier(0);

    const f16* la = &As[buf][0];
    const f16* lb = &Bs[buf][0];
    f16x8 af[8], bf[4];
    // ---- k-sub 0: reads + MFMA
#pragma unroll
    for (int i = 0; i < 8; ++i)
      af[i] = *reinterpret_cast<const f16x8*>(la + raofs + i * 1024);
#pragma unroll
    for (int j = 0; j < 4; ++j)
      bf[j] = *reinterpret_cast<const f16x8*>(lb + rbofs + j * 1024);
#pragma unroll
    for (int i = 0; i < 8; ++i)
#pragma unroll
      for (int j = 0; j < 4; ++j)
        acc[i][j] = __builtin_amdgcn_mfma_f32_16x16x32_f16(af[i], bf[j],
                                                           acc[i][j], 0, 0, 0);
    // ---- k-sub 1: reads (k-chunk ^4 under the swizzle == offset ^32)
#pragma unroll
    for (int i = 0; i < 8; ++i)
      af[i] = *reinterpret_cast<const f16x8*>(la + ((raofs + i * 1024) ^ 32));
#pragma unroll
    for (int j = 0; j < 4; ++j)
      bf[j] = *reinterpret_cast<const f16x8*>(lb + ((rbofs + j * 1024) ^ 32));
    asm volatile("s_waitcnt lgkmcnt(0)" ::: "memory");
    __builtin_amdgcn_sched_barrier(0);
    __builtin_amdgcn_s_barrier();   // all waves finished reading buf
    __builtin_amdgcn_sched_barrier(0);
    if (it + 2 < nit) {
      gA += 64; gB += 64;
      STAGE(buf);                   // refill just-read buffer with tile t+2
    }
#pragma unroll
    for (int i = 0; i < 8; ++i)
#pragma unroll
      for (int j = 0; j < 4; ++j)
        acc[i][j] = __builtin_amdgcn_mfma_f32_16x16x32_f16(af[i], bf[j],
                                                           acc[i][j], 0, 0, 0);
  }
#undef STAGE

  // C/D layout (verified m89/m91, dtype-independent): col=lane&15, row=(lane>>4)*4+reg
  const int col = lane & 15;
  const int rq = kk * 4;
#pragma unroll
  for (int i = 0; i < 8; ++i) {
    const int r0 = wr * 128 + i * 16 + rq;
#pragma unroll
    for (int j = 0; j < 4; ++j) {
      const int cidx = wn * 64 + j * 16 + col;
#pragma unroll
      for (int r = 0; r < 4; ++r) {
        const float v = acc[i][j][r];
        if (ATOMIC)
          atomicAdd(&Cp[(size_t)(r0 + r) * ldc + cidx], v);
        else
          Cp[(size_t)(r0 + r) * ldc + cidx] = v;
      }
    }
  }
}

// ---------------------------------------------------------------------------
// Kernel C: row softmax over 768 logits (SCALE applied here), fp32 -> fp16.
// ---------------------------------------------------------------------------
__global__ __launch_bounds__(256) void k_softmax(const float* __restrict__ S,
                                                 f16* __restrict__ P) {
  const int row = blockIdx.x * 4 + (threadIdx.x >> 6);
  const int lane = threadIdx.x & 63;
  const float* s = S + (size_t)row * CC;
  float v[12];
#pragma unroll
  for (int j = 0; j < 3; ++j) {
    const float4 t = *reinterpret_cast<const float4*>(&s[j * 256 + lane * 4]);
    v[j * 4 + 0] = t.x * SCALE_F;
    v[j * 4 + 1] = t.y * SCALE_F;
    v[j * 4 + 2] = t.z * SCALE_F;
    v[j * 4 + 3] = t.w * SCALE_F;
  }
  float m = v[0];
#pragma unroll
  for (int j = 1; j < 12; ++j) m = fmaxf(m, v[j]);
#pragma unroll
  for (int off = 32; off >= 1; off >>= 1) m = fmaxf(m, __shfl_xor(m, off, 64));
  float sum = 0.f;
#pragma unroll
  for (int j = 0; j < 12; ++j) {
    v[j] = __expf(v[j] - m);
    sum += v[j];
  }
#pragma unroll
  for (int off = 32; off >= 1; off >>= 1) sum += __shfl_xor(sum, off, 64);
  const float inv = 1.0f / sum;
  f16* p = P + (size_t)row * CC;
#pragma unroll
  for (int j = 0; j < 3; ++j) {
    f16x4 o = {(f16)(v[j * 4 + 0] * inv), (f16)(v[j * 4 + 1] * inv),
               (f16)(v[j * 4 + 2] * inv), (f16)(v[j * 4 + 3] * inv)};
    *reinterpret_cast<f16x4*>(&p[j * 256 + lane * 4]) = o;
  }
}

// ---------------------------------------------------------------------------
extern "C" void kernel_launch(void* const* d_in, const int* in_sizes, int n_in,
                              void* d_out, int out_size, void* d_ws,
                              size_t ws_size, hipStream_t stream) {
  const float* x1 = (const float*)d_in[0];
  const float* x2 = (const float*)d_in[1];
  float* out = (float*)d_out;

  const size_t elems = (size_t)NB * NN * CC;  // 25165824
  // x1t/x2t live in d_out (2 * f16 arrays == out fp32 bytes exactly);
  // GEMM2 overwrites out only after GEMM1 consumed them.
  f16* x1t = (f16*)d_out;
  f16* x2t = x1t + elems;
  char* ws = (char*)d_ws;
  f16* x2b = (f16*)ws;                                     // 50.3 MB
  float* S = (float*)(ws + elems * 2);                     // 18.9 MB
  f16* P = (f16*)(ws + elems * 2 + (size_t)NB * CC * CC * 4);  // 9.4 MB
  const size_t need =
      elems * 2 + (size_t)NB * CC * CC * 4 + (size_t)NB * CC * CC * 2;
  if (ws_size < need) return;  // cannot run without scratch

  // A) convert + transpose (128n x 64c tiles)
  k_convert<<<dim3(NN / 128, CC / 64, 2 * NB), 256, 0, stream>>>(x1, x2, x1t,
                                                                 x2t, x2b);
  // B) S = x1t . x2t^T  (split-K x3 uneven, atomic accumulate; S pre-zeroed)
  hipMemsetAsync(S, 0, (size_t)NB * CC * CC * 4, stream);
  k_gemm_bt<true, 1><<<dim3(9 * NB * 3), 512, 0, stream>>>(
      x1t, x2t, S, 1344, NN, NN, CC, (size_t)CC * NN, (size_t)CC * NN,
      (size_t)CC * CC);
  // C) P = softmax(SCALE * S) as fp16
  k_softmax<<<dim3(NB * CC / 4), 256, 0, stream>>>(S, P);
  // D) out = P . x2b^T
  k_gemm_bt<false, 2><<<dim3(16 * 3 * NB), 512, 0, stream>>>(
      P, x2b, out, CC, CC, CC, NN, (size_t)CC * CC, (size_t)NN * CC,
      (size_t)CC * NN);
}

// Round 5
// 344.112 us; speedup vs baseline: 1.2010x; 1.1604x over previous
//
#include <hip/hip_runtime.h>
#include <stdint.h>

typedef _Float16 f16;
typedef _Float16 f16x4 __attribute__((ext_vector_type(4)));
typedef _Float16 f16x8 __attribute__((ext_vector_type(8)));
typedef float f32x4 __attribute__((ext_vector_type(4)));

#define NB 8
#define NN 4096
#define CC 768
#define SCALE_F 0.10206207261596577f  // 96^-0.5

// component i of a float4 (folds statically under #pragma unroll)
#define CMP(v, i) ((i) == 0 ? (v).x : (i) == 1 ? (v).y : (i) == 2 ? (v).z : (v).w)

// ---------------------------------------------------------------------------
// Kernel 1: S_part[ks] = x1^T . x2 over the ks-th n-range (no intermediates!)
//
// The fp32->f16 convert + transpose is FUSED into staging: the standalone
// convert kernel was pinned at ~100us / 2.5 TB/s across 3 implementations
// (latency-, LDS-, and coalescing-fixes all null) -> deleted entirely.
//
// 256x256 tile, BK=64 (n), 8 waves (2Mx4N, wave tile 128x64).
// Staging (per operand, per K-step): thread (nq=lane&7, cq=wave*8+lane>>3)
// loads 8 x float4 = rows nq*8+j, cols cq*4.. of x[n][c] (per instr: 8 rows
// x 128B contiguous = 16 lines, fully coalesced), converts (RNE casts),
// writes transposed: 4 x ds_write_b128, row c=cq*4+i, chunk nq^(c&7).
// Swizzle audit: write quad = (lane&7)^(4*((lane>>3)&1)+i) -> 8 lanes/quad,
// distinct rows = conflict-free; frag-read quad likewise (verified 0
// conflicts in rounds 2-4 with the identical read pattern).
//
// Pipeline: loads(t+1) in regs across iter t (compiler inserts counted
// vmcnt at use); ONE barrier/iter (reg-staged ds_writes are wave-ordered,
// so no GLDS-vs-reader race; barrier needs only lgkmcnt(0)).
// Staging sits between the two K=32 MFMA halves to overlap.
//
// Split-K x3 (1344/1344/1408) -> 216 blocks (27/XCD, b=xcd), PLAIN stores
// to 3 partial buffers; softmax sums them (no atomics, no memset).
// ---------------------------------------------------------------------------
__global__ __launch_bounds__(512, 2) void k_gemm1(
    const float* __restrict__ x1, const float* __restrict__ x2,
    float* __restrict__ Sp) {
  __shared__ __align__(16) f16 As[2][256 * 64];
  __shared__ __align__(16) f16 Bs[2][256 * 64];

  const int lin = blockIdx.x;
  const int b = lin & 7;  // one batch per XCD
  const int slot = lin >> 3;
  const int ks = slot / 9;  // 0..2
  const int item = slot % 9;
  const int bx = item % 3, by = item / 3;
  const int k0 = ks * 1344;
  const int nit = (ks == 2) ? 22 : 21;  // 21/21/22 * 64 = 4096

  const int tid = threadIdx.x;
  const int wave = tid >> 6, lane = tid & 63;

  // staging map
  const int nq = lane & 7;                 // n-octet within K-step
  const int cq = wave * 8 + (lane >> 3);   // 0..63 -> c-chunk of 4
  const float* gA =
      x1 + (size_t)b * NN * CC + (size_t)(k0 + nq * 8) * CC + by * 256 + cq * 4;
  const float* gB =
      x2 + (size_t)b * NN * CC + (size_t)(k0 + nq * 8) * CC + bx * 256 + cq * 4;
  int wofs[4];
#pragma unroll
  for (int i = 0; i < 4; ++i) {
    const int c = cq * 4 + i;
    wofs[i] = c * 64 + ((nq ^ (c & 7)) << 3);
  }

  // fragment map (layout identical to rounds 2-4; verified conflict-free)
  const int wr = wave >> 2, wn = wave & 3;
  const int mrow = lane & 15, kk = lane >> 4;
  const int asw = (kk ^ (mrow & 7)) << 3;
  const int raofs = (wr * 128 + mrow) * 64 + asw;
  const int rbofs = (wn * 64 + mrow) * 64 + asw;

  f32x4 acc[8][4] = {};
  float4 la[8], lb[8];

#define G1LOAD()                                                             \
  do {                                                                       \
    _Pragma("unroll") for (int j = 0; j < 8; ++j) {                          \
      la[j] = *reinterpret_cast<const float4*>(&gA[(size_t)j * CC]);         \
      lb[j] = *reinterpret_cast<const float4*>(&gB[(size_t)j * CC]);         \
    }                                                                        \
    gA += (size_t)64 * CC;                                                   \
    gB += (size_t)64 * CC;                                                   \
  } while (0)

#define G1WRITE(bufi)                                                        \
  do {                                                                       \
    _Pragma("unroll") for (int i = 0; i < 4; ++i) {                          \
      f16x8 ha, hb;                                                          \
      _Pragma("unroll") for (int j = 0; j < 8; ++j) {                        \
        ha[j] = (f16)CMP(la[j], i);                                          \
        hb[j] = (f16)CMP(lb[j], i);                                          \
      }                                                                      \
      *reinterpret_cast<f16x8*>(&As[bufi][wofs[i]]) = ha;                    \
      *reinterpret_cast<f16x8*>(&Bs[bufi][wofs[i]]) = hb;                    \
    }                                                                        \
  } while (0)

  G1LOAD();     // tile 0 -> regs
  G1WRITE(0);   // (compiler waits the loads)
  G1LOAD();     // tile 1 -> regs

  for (int it = 0; it < nit; ++it) {
    const int cur = it & 1, nxt = cur ^ 1;
    asm volatile("s_waitcnt lgkmcnt(0)" ::: "memory");  // my ds_writes done
    __builtin_amdgcn_s_barrier();
    __builtin_amdgcn_sched_barrier(0);
    const f16* pa = &As[cur][0];
    const f16* pb = &Bs[cur][0];
    f16x8 af[4], bf[4];
    // ---- k-sub 0
#pragma unroll
    for (int j = 0; j < 4; ++j)
      bf[j] = *reinterpret_cast<const f16x8*>(pb + rbofs + j * 1024);
#pragma unroll
    for (int h = 0; h < 2; ++h) {
#pragma unroll
      for (int i = 0; i < 4; ++i)
        af[i] = *reinterpret_cast<const f16x8*>(pa + raofs + (h * 4 + i) * 1024);
#pragma unroll
      for (int i = 0; i < 4; ++i)
#pragma unroll
        for (int j = 0; j < 4; ++j)
          acc[h * 4 + i][j] = __builtin_amdgcn_mfma_f32_16x16x32_f16(
              af[i], bf[j], acc[h * 4 + i][j], 0, 0, 0);
    }
    // ---- staging for tile it+1 (between the MFMA halves)
    if (it + 1 < nit) {
      __builtin_amdgcn_sched_barrier(0);
      G1WRITE(nxt);
      if (it + 2 < nit) G1LOAD();
      __builtin_amdgcn_sched_barrier(0);
    }
    // ---- k-sub 1 (chunk ^4 under the swizzle == elem offset ^32)
#pragma unroll
    for (int j = 0; j < 4; ++j)
      bf[j] = *reinterpret_cast<const f16x8*>(pb + ((rbofs + j * 1024) ^ 32));
#pragma unroll
    for (int h = 0; h < 2; ++h) {
#pragma unroll
      for (int i = 0; i < 4; ++i)
        af[i] = *reinterpret_cast<const f16x8*>(
            pa + ((raofs + (h * 4 + i) * 1024) ^ 32));
#pragma unroll
      for (int i = 0; i < 4; ++i)
#pragma unroll
        for (int j = 0; j < 4; ++j)
          acc[h * 4 + i][j] = __builtin_amdgcn_mfma_f32_16x16x32_f16(
              af[i], bf[j], acc[h * 4 + i][j], 0, 0, 0);
    }
  }
#undef G1LOAD
#undef G1WRITE

  // plain stores to this ks's partial buffer (no atomics)
  float* Cp = Sp + (size_t)ks * NB * CC * CC + (size_t)b * CC * CC +
              (size_t)by * 256 * CC + bx * 256;
  const int col = lane & 15;
  const int rq = kk * 4;
#pragma unroll
  for (int i = 0; i < 8; ++i) {
    const int r0 = wr * 128 + i * 16 + rq;
#pragma unroll
    for (int j = 0; j < 4; ++j) {
      const int cidx = wn * 64 + j * 16 + col;
#pragma unroll
      for (int r = 0; r < 4; ++r)
        Cp[(size_t)(r0 + r) * CC + cidx] = acc[i][j][r];
    }
  }
}

// ---------------------------------------------------------------------------
// Kernel 2: out = P . x2^T-style (C[c][n'] = sum_d P[c][d] * x2[n'][d]).
// A = P (f16, natural row-major): reg-stage 4 x f16x8 loads + 4 b128 writes.
// B = x2 (fp32, natural row-major): reg-stage 8 x float4 + cvt + 8 b64
// writes (no transpose needed). Same LDS layout/swizzle + skeleton as gemm1.
// Grid 16bx x 3by x 8b = 384, b = xcd.
// ---------------------------------------------------------------------------
__global__ __launch_bounds__(512, 2) void k_gemm2(
    const f16* __restrict__ P, const float* __restrict__ x2,
    float* __restrict__ out) {
  __shared__ __align__(16) f16 As[2][256 * 64];
  __shared__ __align__(16) f16 Bs[2][256 * 64];

  const int lin = blockIdx.x;
  const int b = lin & 7;
  const int slot = lin >> 3;
  const int by = slot % 3;   // 3 consecutive tiles share the B slab
  const int bx = slot / 3;   // 0..15
  const int nit = 12;        // K = 768 = 12 * 64

  const int tid = threadIdx.x;
  const int wave = tid >> 6, lane = tid & 63;

  // A staging map: k-chunk ak = tid&7 (const), rows ar = i*64 + (tid>>3)
  const int ak = tid & 7;
  const int ar = tid >> 3;  // 0..63
  const f16* gP =
      P + (size_t)b * CC * CC + (size_t)(by * 256 + ar) * CC + ak * 8;
  int wofsa[4];
#pragma unroll
  for (int i = 0; i < 4; ++i)
    wofsa[i] = (i * 64 + ar) * 64 + ((ak ^ (ar & 7)) << 3);

  // B staging map: fp32-chunk bk = tid&15 (const), rows br_q = q*32 + (tid>>4)
  const int bk = tid & 15;
  const int br = tid >> 4;  // 0..31
  const float* gB =
      x2 + (size_t)b * NN * CC + (size_t)(bx * 256 + br) * CC + bk * 4;
  int wofsb[8];
#pragma unroll
  for (int q = 0; q < 8; ++q)
    wofsb[q] =
        (q * 32 + br) * 64 + (((bk >> 1) ^ (br & 7)) << 3) + ((bk & 1) << 2);

  // fragment map (same as gemm1)
  const int wr = wave >> 2, wn = wave & 3;
  const int mrow = lane & 15, kk = lane >> 4;
  const int asw = (kk ^ (mrow & 7)) << 3;
  const int raofs = (wr * 128 + mrow) * 64 + asw;
  const int rbofs = (wn * 64 + mrow) * 64 + asw;

  f32x4 acc[8][4] = {};
  f16x8 lpa[4];
  float4 lb[8];

#define G2LOAD()                                                             \
  do {                                                                       \
    _Pragma("unroll") for (int i = 0; i < 4; ++i) lpa[i] =                   \
        *reinterpret_cast<const f16x8*>(&gP[(size_t)(i * 64) * CC]);         \
    _Pragma("unroll") for (int q = 0; q < 8; ++q) lb[q] =                    \
        *reinterpret_cast<const float4*>(&gB[(size_t)(q * 32) * CC]);        \
    gP += 64;                                                                \
    gB += 64;                                                                \
  } while (0)

#define G2WRITE(bufi)                                                        \
  do {                                                                       \
    _Pragma("unroll") for (int i = 0; i < 4; ++i)                            \
        *reinterpret_cast<f16x8*>(&As[bufi][wofsa[i]]) = lpa[i];             \
    _Pragma("unroll") for (int q = 0; q < 8; ++q) {                          \
      f16x4 h = {(f16)lb[q].x, (f16)lb[q].y, (f16)lb[q].z, (f16)lb[q].w};    \
      *reinterpret_cast<f16x4*>(&Bs[bufi][wofsb[q]]) = h;                    \
    }                                                                        \
  } while (0)

  G2LOAD();
  G2WRITE(0);
  G2LOAD();

  for (int it = 0; it < nit; ++it) {
    const int cur = it & 1, nxt = cur ^ 1;
    asm volatile("s_waitcnt lgkmcnt(0)" ::: "memory");
    __builtin_amdgcn_s_barrier();
    __builtin_amdgcn_sched_barrier(0);
    const f16* pa = &As[cur][0];
    const f16* pb = &Bs[cur][0];
    f16x8 af[4], bf[4];
#pragma unroll
    for (int j = 0; j < 4; ++j)
      bf[j] = *reinterpret_cast<const f16x8*>(pb + rbofs + j * 1024);
#pragma unroll
    for (int h = 0; h < 2; ++h) {
#pragma unroll
      for (int i = 0; i < 4; ++i)
        af[i] = *reinterpret_cast<const f16x8*>(pa + raofs + (h * 4 + i) * 1024);
#pragma unroll
      for (int i = 0; i < 4; ++i)
#pragma unroll
        for (int j = 0; j < 4; ++j)
          acc[h * 4 + i][j] = __builtin_amdgcn_mfma_f32_16x16x32_f16(
              af[i], bf[j], acc[h * 4 + i][j], 0, 0, 0);
    }
    if (it + 1 < nit) {
      __builtin_amdgcn_sched_barrier(0);
      G2WRITE(nxt);
      if (it + 2 < nit) G2LOAD();
      __builtin_amdgcn_sched_barrier(0);
    }
#pragma unroll
    for (int j = 0; j < 4; ++j)
      bf[j] = *reinterpret_cast<const f16x8*>(pb + ((rbofs + j * 1024) ^ 32));
#pragma unroll
    for (int h = 0; h < 2; ++h) {
#pragma unroll
      for (int i = 0; i < 4; ++i)
        af[i] = *reinterpret_cast<const f16x8*>(
            pa + ((raofs + (h * 4 + i) * 1024) ^ 32));
#pragma unroll
      for (int i = 0; i < 4; ++i)
#pragma unroll
        for (int j = 0; j < 4; ++j)
          acc[h * 4 + i][j] = __builtin_amdgcn_mfma_f32_16x16x32_f16(
              af[i], bf[j], acc[h * 4 + i][j], 0, 0, 0);
    }
  }
#undef G2LOAD
#undef G2WRITE

  float* Cp = out + (size_t)b * CC * NN + (size_t)by * 256 * NN + bx * 256;
  const int col = lane & 15;
  const int rq = kk * 4;
#pragma unroll
  for (int i = 0; i < 8; ++i) {
    const int r0 = wr * 128 + i * 16 + rq;
#pragma unroll
    for (int j = 0; j < 4; ++j) {
      const int cidx = wn * 64 + j * 16 + col;
#pragma unroll
      for (int r = 0; r < 4; ++r)
        Cp[(size_t)(r0 + r) * NN + cidx] = acc[i][j][r];
    }
  }
}

// ---------------------------------------------------------------------------
// Kernel 3: row softmax over 768 logits; sums the 3 split-K partials of S
// (replaces atomics+memset), applies SCALE, writes fp16 P.
// ---------------------------------------------------------------------------
__global__ __launch_bounds__(256) void k_softmax(const float* __restrict__ S,
                                                 f16* __restrict__ Pm) {
  const size_t PS = (size_t)NB * CC * CC;
  const int row = blockIdx.x * 4 + (threadIdx.x >> 6);
  const int lane = threadIdx.x & 63;
  const float* s0 = S + (size_t)row * CC;
  float v[12];
#pragma unroll
  for (int j = 0; j < 3; ++j) {
    const int o = j * 256 + lane * 4;
    const float4 t0 = *reinterpret_cast<const float4*>(&s0[o]);
    const float4 t1 = *reinterpret_cast<const float4*>(&s0[o + PS]);
    const float4 t2 = *reinterpret_cast<const float4*>(&s0[o + 2 * PS]);
    v[j * 4 + 0] = (t0.x + t1.x + t2.x) * SCALE_F;
    v[j * 4 + 1] = (t0.y + t1.y + t2.y) * SCALE_F;
    v[j * 4 + 2] = (t0.z + t1.z + t2.z) * SCALE_F;
    v[j * 4 + 3] = (t0.w + t1.w + t2.w) * SCALE_F;
  }
  float m = v[0];
#pragma unroll
  for (int j = 1; j < 12; ++j) m = fmaxf(m, v[j]);
#pragma unroll
  for (int off = 32; off >= 1; off >>= 1) m = fmaxf(m, __shfl_xor(m, off, 64));
  float sum = 0.f;
#pragma unroll
  for (int j = 0; j < 12; ++j) {
    v[j] = __expf(v[j] - m);
    sum += v[j];
  }
#pragma unroll
  for (int off = 32; off >= 1; off >>= 1) sum += __shfl_xor(sum, off, 64);
  const float inv = 1.0f / sum;
  f16* p = Pm + (size_t)row * CC;
#pragma unroll
  for (int j = 0; j < 3; ++j) {
    f16x4 o = {(f16)(v[j * 4 + 0] * inv), (f16)(v[j * 4 + 1] * inv),
               (f16)(v[j * 4 + 2] * inv), (f16)(v[j * 4 + 3] * inv)};
    *reinterpret_cast<f16x4*>(&p[j * 256 + lane * 4]) = o;
  }
}

// ---------------------------------------------------------------------------
extern "C" void kernel_launch(void* const* d_in, const int* in_sizes, int n_in,
                              void* d_out, int out_size, void* d_ws,
                              size_t ws_size, hipStream_t stream) {
  const float* x1 = (const float*)d_in[0];
  const float* x2 = (const float*)d_in[1];
  float* out = (float*)d_out;

  const size_t PS = (size_t)NB * CC * CC;  // 4.72M elems
  char* ws = (char*)d_ws;
  float* S = (float*)ws;                   // 3 partials: 56.6 MB
  f16* P = (f16*)(ws + 3 * PS * 4);        // 9.4 MB
  const size_t need = 3 * PS * 4 + PS * 2;
  if (ws_size < need) return;

  // 1) S_parts = x1^T.x2 (fused fp32->f16 convert+transpose in staging)
  k_gemm1<<<dim3(9 * 3 * NB), 512, 0, stream>>>(x1, x2, S);
  // 2) P = softmax(SCALE * sum(S_parts)) as fp16
  k_softmax<<<dim3(NB * CC / 4), 256, 0, stream>>>(S, P);
  // 3) out = P . x2^T (B converted fp32->f16 in staging)
  k_gemm2<<<dim3(16 * 3 * NB), 512, 0, stream>>>(P, x2, out);
}